// Round 6
// baseline (485.781 us; speedup 1.0000x reference)
//
#include <hip/hip_runtime.h>

// Problem constants
#define NPOS   158   // 64 query + 94 doc token positions per batch
#define NCH    32    // chains (windows) per block
#define EPITCH 136   // shorts per staged emb row (128 + 8 pad)
#define HP8    264   // bytes per fp8 h row (256 + 8 pad)

// workspace layout (bytes)
#define RKP8_BYTES (2*64*8*64*8)           // rk packed fp8: [dir][nt64][ks8][lane64][j8] = 524288
#define KP_SHORTS  (2*64*4*512)            // k  packed bf16: [dir][nt64][ks4][lane64][j8]
#define XZ_HALFS   ((size_t)2*128*158*1024)
#define OFF_KP     ((size_t)1048576)
#define OFF_XZ     (OFF_KP + (size_t)KP_SHORTS*2)         // 1,572,864
#define OFF_HOUT   (OFF_XZ + XZ_HALFS*2)                  // 84,410,368

typedef __attribute__((ext_vector_type(8))) short    short8;
typedef __attribute__((ext_vector_type(4))) short    short4v;
typedef __attribute__((ext_vector_type(4))) float    float4v;
typedef __attribute__((ext_vector_type(8))) _Float16 half8;
typedef __attribute__((ext_vector_type(4))) _Float16 half4;

__device__ __forceinline__ unsigned short f2bf(float x){
  unsigned int u = __builtin_bit_cast(unsigned int, x);
  u += 0x7FFFu + ((u >> 16) & 1u);           // round-to-nearest-even
  return (unsigned short)(u >> 16);
}

// OCP e4m3fn conversion via HW converter (guarded builtin + asm fallback).
__device__ __forceinline__ unsigned char f2fp8(float x){
#if __has_builtin(__builtin_amdgcn_cvt_pk_fp8_f32)
  unsigned int p = (unsigned int)__builtin_amdgcn_cvt_pk_fp8_f32(x, x, 0, false);
#else
  unsigned int p;
  asm("v_cvt_pk_fp8_f32 %0, %1, %2" : "=v"(p) : "v"(x), "v"(x));
#endif
  return (unsigned char)(p & 0xffu);
}

// Linear-interpolated LDS table lookup: T has N+1 entries covering
// [-12,12]; t = x*scale+off in [0,N]; clamped; y = lerp(T[i],T[i+1],fr).
// ~7 full-rate VALU + 2 ds_read_b32 -- replaces quarter-rate exp+rcp
// (which occupy the VALU issue slot ~16 cy each at wave64).
__device__ __forceinline__ float lut1(const float* __restrict__ T, float x,
                                      float scale, float off, float hi){
  float t = __builtin_fmaf(x, scale, off);
  t = fminf(fmaxf(t, 0.0f), hi);
  int i = (int)t;
  float fr = t - (float)i;
  float y0 = T[i];
  float y1 = T[i+1];
  return __builtin_fmaf(y1 - y0, fr, y0);
}

// ---------------------------------------------------------------------------
// Pack rk (256x1024) per dir into fp8 MFMA B-fragment lane order:
// byte j of lane l for tile (nt,ks) = W[k = ks*32+(l>>4)*8+j][col = nt*16+(l&15)].
// Pack k (128x1024) per dir into bf16 B-fragment order (for xzgemm), unchanged.
// ---------------------------------------------------------------------------
__global__ void prepack(const float* __restrict__ kf, const float* __restrict__ rkf,
                        const float* __restrict__ kb, const float* __restrict__ rkb,
                        unsigned char* __restrict__ rkp8, unsigned short* __restrict__ kp){
  int idx = blockIdx.x*256 + threadIdx.x;
  if (idx < RKP8_BYTES){
    int j = idx & 7, lane = (idx>>3)&63, ks = (idx>>9)&7, nt = (idx>>12)&63, d = idx>>18;
    const float* RK = d ? rkb : rkf;
    int k   = ks*32 + (lane>>4)*8 + j;
    int col = nt*16 + (lane&15);
    rkp8[idx] = f2fp8(RK[k*1024 + col]);
  } else {
    int i2 = idx - RKP8_BYTES;
    int j = i2 & 7, lane = (i2>>3)&63, ks = (i2>>9)&3, nt = (i2>>11)&63, d = i2>>17;
    const float* K = d ? kb : kf;
    int k   = ks*32 + (lane>>4)*8 + j;
    int col = nt*16 + (lane&15);
    kp[i2] = f2bf(K[k*1024 + col]);
  }
}

// ---------------------------------------------------------------------------
// xz[dir][bat][pos][1024] (fp16) = emb @ k + bias.
// Inner layout: [pos][unit j 256][gate 4] -- the recurrent kernel's lane
// (owning hidden unit j) reads its element's 4 gate pre-activations as ONE
// 8B half4 load. Grid: 128 bat x 2 dir x 5 pos-tiles of 32.
// ---------------------------------------------------------------------------
__launch_bounds__(512)
__global__ void xzgemm(const int* __restrict__ inputs, const float* __restrict__ emb,
                       const unsigned short* __restrict__ kpack,
                       const float* __restrict__ b_f, const float* __restrict__ b_b,
                       _Float16* __restrict__ xz){
  __shared__ int tokp[32];
  __shared__ __align__(16) short e_lds[32*EPITCH];
  const int bid = blockIdx.x;
  const int pt  = bid % 5;
  const int bd  = bid / 5;
  const int bat = bd & 127, dir = bd >> 7;
  const int tid = threadIdx.x, lane = tid & 63, wv = tid >> 6;
  const int lc  = lane & 15, q = lane >> 4;

  for (int i = tid; i < 32*EPITCH; i += 512) e_lds[i] = 0;
  if (tid < 32){
    int p = pt*32 + tid;
    tokp[tid] = (p < NPOS) ? inputs[bat*NPOS + p] : 0;
  }
  __syncthreads();
  for (int idx = tid; idx < 32*32; idx += 512){
    int i = idx >> 5, c4 = (idx & 31) << 2;
    int p = pt*32 + i;
    if (p < NPOS){
      float4v v = *(const float4v*)(emb + (long)tokp[i]*128 + c4);
      short4v s;
      s[0]=(short)f2bf(v[0]); s[1]=(short)f2bf(v[1]);
      s[2]=(short)f2bf(v[2]); s[3]=(short)f2bf(v[3]);
      *(short4v*)&e_lds[i*EPITCH + c4] = s;
    }
  }
  __syncthreads();

  const float* bias = dir ? b_b : b_f;
  float4v acc[2][8];
  #pragma unroll
  for (int g = 0; g < 4; ++g)
    #pragma unroll
    for (int tj = 0; tj < 2; ++tj){
      float bv = bias[g*256 + wv*32 + tj*16 + lc];
      acc[0][g*2+tj] = (float4v){bv,bv,bv,bv};
      acc[1][g*2+tj] = acc[0][g*2+tj];
    }

  const short8* KP = (const short8*)kpack + (long)dir*64*4*64;
  #pragma unroll
  for (int ks = 0; ks < 4; ++ks){
    short8 a0 = *(const short8*)&e_lds[lc*EPITCH + ks*32 + q*8];
    short8 a1 = *(const short8*)&e_lds[(16+lc)*EPITCH + ks*32 + q*8];
    #pragma unroll
    for (int n = 0; n < 8; ++n){
      int g = n >> 1, tj = n & 1;
      int nt = g*16 + wv*2 + tj;
      short8 b = KP[(nt*4 + ks)*64 + lane];
      acc[0][n] = __builtin_amdgcn_mfma_f32_16x16x32_bf16(a0, b, acc[0][n], 0, 0, 0);
      acc[1][n] = __builtin_amdgcn_mfma_f32_16x16x32_bf16(a1, b, acc[1][n], 0, 0, 0);
    }
  }

  _Float16* xzb = xz + ((long)(dir*128 + bat))*NPOS*1024;
  #pragma unroll
  for (int mt = 0; mt < 2; ++mt)
    #pragma unroll
    for (int r = 0; r < 4; ++r){
      int row = mt*16 + q*4 + r;
      int p = pt*32 + row;
      if (p < NPOS){
        #pragma unroll
        for (int tj = 0; tj < 2; ++tj){
          half4 hv;
          #pragma unroll
          for (int g = 0; g < 4; ++g) hv[g] = (_Float16)acc[mt][g*2+tj][r];
          int j = wv*32 + tj*16 + lc;   // hidden unit
          *(half4*)(xzb + (long)p*1024 + j*4) = hv;
        }
      }
    }
}

// ---------------------------------------------------------------------------
// Recurrent kernel: block = (batch, dir), 32 chains, 64 steps, K=256 (h only).
// 1024 threads (16 waves -> 4 waves/SIMD). rk ENTIRELY in VGPRs (fp8, 64
// regs/wave); h quantized to fp8 in double-buffered LDS; h/c state exact f32
// in registers; xz served from the fp16 LDS sliding window.
// NEW: sigmoid/tanh via linear-interp LDS LUTs (sigT 1024 intervals, tanT
// 2048 intervals over [-12,12]) -- removes all quarter-rate v_exp/v_rcp
// issue cycles (~60% of VALU issue at round-5) from the step loop.
// ---------------------------------------------------------------------------
__launch_bounds__(1024, 4)
__global__ void lstm_rec(const int* __restrict__ inputs, const _Float16* __restrict__ xz,
                         const unsigned char* __restrict__ rkpack8,
                         const float* __restrict__ wci_f, const float* __restrict__ wcf_f,
                         const float* __restrict__ wco_f,
                         const float* __restrict__ wci_b, const float* __restrict__ wcf_b,
                         const float* __restrict__ wco_b,
                         float* __restrict__ h_out)
{
  __shared__ int tok[NPOS];
  __shared__ __align__(16) unsigned char h8[2][NCH*HP8]; // 2 x 8.25 KB fp8
  __shared__ __align__(16) _Float16 xq[2][1024];         // query rows, slot t&1 (4 KB)
  __shared__ __align__(16) _Float16 xd[32][1024];        // doc rows, slot p&31 (64 KB)
  __shared__ float sigT[1025];                           // sigma over [-12,12]
  __shared__ float tanT[2049];                           // tanh  over [-12,12]

  const int tid  = threadIdx.x;
  const int lane = tid & 63;
  const int wv   = tid >> 6;        // 0..15
  const int lc   = lane & 15;
  const int q    = lane >> 4;
  const int ju   = wv*16 + lc;      // this thread's hidden unit (0..255)
  const int bat  = blockIdx.x & 127;
  const int dir  = blockIdx.x >> 7;

  for (int p = tid; p < NPOS; p += 1024) tok[p] = inputs[bat*NPOS + p];
  for (int i = tid; i < NCH*HP8; i += 1024) h8[0][i] = 0;

  // fill LUTs (once; precise libm is fine here)
  for (int i = tid; i < 1025; i += 1024)
    sigT[i] = 1.0f/(1.0f + __expf(12.0f - (float)i*0.0234375f));
  for (int i = tid; i < 2049; i += 1024)
    tanT[i] = tanhf((float)i*0.01171875f - 12.0f);

  // ---- this wave's rk slice: 4 nt-tiles x 8 ks x 8B = 64 VGPRs ----
  const long* RK8 = (const long*)(rkpack8 + (long)dir*64*8*64*8);
  long rkr[8][4];                   // [ks][g], nt = g*16 + wv
  #pragma unroll
  for (int g = 0; g < 4; ++g){
    int nt = g*16 + wv;
    #pragma unroll
    for (int ks = 0; ks < 8; ++ks)
      rkr[ks][g] = RK8[(nt*8 + ks)*64 + lane];
  }

  const _Float16* xzg = xz + ((long)(dir*128 + bat))*NPOS*1024;
  const int t0 = dir ? 63 : 0;

  // prefill window: query row t0 + doc rows t0+64 .. t0+94 (32 rows, 64 KB)
  for (int i = tid; i < 32*128; i += 1024){
    int rr = i >> 7, c = i & 127;
    int p; _Float16* dst;
    if (rr == 0){ p = t0;           dst = &xq[t0 & 1][0]; }
    else        { p = t0 + 63 + rr; dst = &xd[p & 31][0]; }
    *(half8*)(dst + c*8) = *(const half8*)(xzg + (long)p*1024 + c*8);
  }

  const float* wci = dir ? wci_b : wci_f;
  const float* wcf = dir ? wcf_b : wcf_f;
  const float* wco = dir ? wco_b : wco_f;
  const float wcir = wci[ju], wcfr = wcf[ju], wcor = wco[ju];

  float hreg[2][4], creg[2][4];
  #pragma unroll
  for (int mt = 0; mt < 2; ++mt)
    #pragma unroll
    for (int r = 0; r < 4; ++r){ hreg[mt][r] = 0.f; creg[mt][r] = 0.f; }

  __syncthreads();

  for (int s = 0; s < 64; ++s){
    const int t  = dir ? (63 - s) : s;
    const int rb = s & 1, wb = rb ^ 1;
    const int tn = dir ? (t - 1) : (t + 1);

    // prefetch next-step xz rows: 2 rows x 2 KB = 4 KB; all 1024 threads load
    // one dword NOW, LDS-write just before the barrier (latency hidden under
    // this step's MFMAs+gates). Target slots are guaranteed unread this step.
    unsigned int pref = 0;
    const int prsel = tid >> 9;                    // 0 = query row, 1 = doc row
    const int prq   = tn;
    const int prd   = dir ? (tn + 64) : (tn + 94);
    if (s < 63){
      int c = tid & 511;
      int p = prsel ? prd : prq;
      pref = ((const unsigned int*)(xzg + (long)p*1024))[c];
    }

    // two mt-phases keep only 16 acc regs live at once
    #pragma unroll
    for (int mt = 0; mt < 2; ++mt){
      // acc init from LDS xz window: per r one 8B half4 = 4 gate values
      float4v acc[4];                              // [g], vector index = r
      #pragma unroll
      for (int r = 0; r < 4; ++r){
        int m = mt*16 + q*4 + r;
        const _Float16* srow = (m == 0) ? &xq[t & 1][0] : &xd[(63 + m + t) & 31][0];
        half4 hv = *(const half4*)(srow + ju*4);
        acc[0][r] = (float)hv[0];
        acc[1][r] = (float)hv[1];
        acc[2][r] = (float)hv[2];
        acc[3][r] = (float)hv[3];
      }

      // MFMA over K=256 (8 ks slices); rk fragments straight from VGPRs
      const int arow = (mt*16 + lc)*HP8;
      #pragma unroll
      for (int ks = 0; ks < 8; ++ks){
        long a = *(const long*)&h8[rb][arow + ks*32 + q*8];
        #pragma unroll
        for (int g = 0; g < 4; ++g)
          acc[g] = __builtin_amdgcn_mfma_f32_16x16x32_fp8_fp8(a, rkr[ks][g], acc[g], 0, 0, 0);
      }

      // gates via LUTs: C/D layout row(chain) = q*4+r, col = unit ju
      #pragma unroll
      for (int r = 0; r < 4; ++r){
        int m = mt*16 + q*4 + r;
        int p = (m == 0) ? t : 63 + m + t;
        bool msk = (tok[p] != 0);
        float zi = acc[0][r];
        float zf = acc[1][r];
        float zc = acc[2][r];
        float zo = acc[3][r];
        float c0 = creg[mt][r];
        float ig = lut1(sigT, __builtin_fmaf(c0, wcir, zi), 42.6666667f, 512.0f, 1023.999f);
        float fg = lut1(sigT, __builtin_fmaf(c0, wcfr, zf), 42.6666667f, 512.0f, 1023.999f);
        float tc = lut1(tanT, zc,                           85.3333333f, 1024.0f, 2047.999f);
        float cn = __builtin_fmaf(fg, c0, ig*tc);
        float og = lut1(sigT, __builtin_fmaf(cn, wcor, zo), 42.6666667f, 512.0f, 1023.999f);
        float th = lut1(tanT, cn,                           85.3333333f, 1024.0f, 2047.999f);
        float hn = og*th;
        float hv = msk ? hn : hreg[mt][r];
        float cv = msk ? cn : c0;
        hreg[mt][r] = hv;
        creg[mt][r] = cv;
        h8[wb][m*HP8 + ju] = f2fp8(hv);
      }
    }

    // land the prefetched xz rows (slots free this step; read next step)
    if (s < 63){
      int c = tid & 511;
      _Float16* dst = prsel ? &xd[prd & 31][0] : &xq[prq & 1][0];
      ((unsigned int*)dst)[c] = pref;
    }

    __syncthreads();   // one barrier per step (double-buffered h + xz window)
  }

  #pragma unroll
  for (int mt = 0; mt < 2; ++mt)
    #pragma unroll
    for (int r = 0; r < 4; ++r){
      int m = mt*16 + q*4 + r;
      h_out[(((long)dir*128 + bat)*32 + m)*256 + ju] = hreg[mt][r];
    }
}

// ---------------------------------------------------------------------------
// h_avg = 0.5(h_f + h_b); cos = |q.d|/(|q||d|); softmax over 31 docs.
// ---------------------------------------------------------------------------
__global__ void finalize(const float* __restrict__ h_out, float* __restrict__ out){
  __shared__ float hav[32*256];
  __shared__ float dotl[32], sql[32];
  const int bat = blockIdx.x;
  const int tid = threadIdx.x;
  const float* hf = h_out + (long)bat*8192;
  const float* hb = h_out + (long)(128 + bat)*8192;
  for (int i = tid; i < 8192; i += 256) hav[i] = 0.5f*(hf[i] + hb[i]);
  __syncthreads();
  const int lane = tid & 63, wv = tid >> 6;
  for (int n = wv; n < 32; n += 4){
    float s1 = 0.f, s2 = 0.f;
    for (int j = lane; j < 256; j += 64){
      float a  = hav[n*256 + j];
      float qv = hav[j];
      s1 += a*qv; s2 += a*a;
    }
    #pragma unroll
    for (int off = 32; off; off >>= 1){
      s1 += __shfl_down(s1, off);
      s2 += __shfl_down(s2, off);
    }
    if (lane == 0){ dotl[n] = s1; sql[n] = s2; }
  }
  __syncthreads();
  if (wv == 0){
    float cosv = -1e30f;
    if (lane < 31)
      cosv = fabsf(dotl[lane+1]) / (sqrtf(sql[0]) * sqrtf(sql[lane+1]));
    float mx = cosv;
    #pragma unroll
    for (int off = 32; off; off >>= 1) mx = fmaxf(mx, __shfl_xor(mx, off));
    float e = (lane < 31) ? __expf(cosv - mx) : 0.f;
    float sum = e;
    #pragma unroll
    for (int off = 32; off; off >>= 1) sum += __shfl_xor(sum, off);
    if (lane < 31) out[bat*31 + lane] = e / sum;
  }
}

extern "C" void kernel_launch(void* const* d_in, const int* in_sizes, int n_in,
                              void* d_out, int out_size, void* d_ws, size_t ws_size,
                              hipStream_t stream) {
  const int*   inputs = (const int*)  d_in[0];
  const float* emb    = (const float*)d_in[1];
  const float* k_f    = (const float*)d_in[2];
  const float* rk_f   = (const float*)d_in[3];
  const float* b_f    = (const float*)d_in[4];
  const float* wci_f  = (const float*)d_in[5];
  const float* wcf_f  = (const float*)d_in[6];
  const float* wco_f  = (const float*)d_in[7];
  const float* k_b    = (const float*)d_in[8];
  const float* rk_b   = (const float*)d_in[9];
  const float* b_b    = (const float*)d_in[10];
  const float* wci_b  = (const float*)d_in[11];
  const float* wcf_b  = (const float*)d_in[12];
  const float* wco_b  = (const float*)d_in[13];

  unsigned char*  rkp8 = (unsigned char*) d_ws;
  unsigned short* kp   = (unsigned short*)((char*)d_ws + OFF_KP);
  _Float16*       xzp  = (_Float16*)     ((char*)d_ws + OFF_XZ);
  float*          hout = (float*)        ((char*)d_ws + OFF_HOUT);

  prepack<<<(RKP8_BYTES + KP_SHORTS)/256, 256, 0, stream>>>(k_f, rk_f, k_b, rk_b, rkp8, kp);
  xzgemm <<<128*2*5, 512, 0, stream>>>(inputs, emb, kp, b_f, b_b, xzp);
  lstm_rec<<<256, 1024, 0, stream>>>(inputs, xzp, rkp8,
                                     wci_f, wcf_f, wco_f,
                                     wci_b, wcf_b, wco_b, hout);
  finalize<<<128, 256, 0, stream>>>(hout, (float*)d_out);
}

// Round 7
// 399.163 us; speedup vs baseline: 1.2170x; 1.2170x over previous
//
#include <hip/hip_runtime.h>

// Problem constants
#define NPOS   158   // 64 query + 94 doc token positions per batch
#define NCH    32    // chains (windows) per block
#define EPITCH 136   // shorts per staged emb row (128 + 8 pad)
#define HP8    264   // bytes per fp8 h row (256 + 8 pad)

// workspace layout (bytes)
#define RKP8_BYTES (2*64*8*64*8)           // rk packed fp8: [dir][nt64][ks8][lane64][j8] = 524288
#define KP_SHORTS  (2*64*4*512)            // k  packed bf16: [dir][nt64][ks4][lane64][j8]
#define XZ_HALFS   ((size_t)2*128*158*1024)
#define OFF_KP     ((size_t)1048576)
#define OFF_XZ     (OFF_KP + (size_t)KP_SHORTS*2)         // 1,572,864
#define OFF_HOUT   (OFF_XZ + XZ_HALFS*2)                  // 84,410,368

typedef __attribute__((ext_vector_type(8))) short    short8;
typedef __attribute__((ext_vector_type(4))) short    short4v;
typedef __attribute__((ext_vector_type(4))) float    float4v;
typedef __attribute__((ext_vector_type(8))) _Float16 half8;
typedef __attribute__((ext_vector_type(4))) _Float16 half4;

__device__ __forceinline__ unsigned short f2bf(float x){
  unsigned int u = __builtin_bit_cast(unsigned int, x);
  u += 0x7FFFu + ((u >> 16) & 1u);           // round-to-nearest-even
  return (unsigned short)(u >> 16);
}

// OCP e4m3fn conversion via HW converter (guarded builtin + asm fallback).
__device__ __forceinline__ unsigned char f2fp8(float x){
#if __has_builtin(__builtin_amdgcn_cvt_pk_fp8_f32)
  unsigned int p = (unsigned int)__builtin_amdgcn_cvt_pk_fp8_f32(x, x, 0, false);
#else
  unsigned int p;
  asm("v_cvt_pk_fp8_f32 %0, %1, %2" : "=v"(p) : "v"(x), "v"(x));
#endif
  return (unsigned char)(p & 0xffu);
}

// Fast transcendentals: raw v_exp_f32 / v_rcp_f32 (~1 ulp), avoiding hipcc's
// precise-division sequence (v_div_scale/fmas/fixup, ~10 inst per divide).
__device__ __forceinline__ float fexp2(float x){
#if __has_builtin(__builtin_amdgcn_exp2f)
  return __builtin_amdgcn_exp2f(x);
#else
  float r; asm("v_exp_f32 %0, %1" : "=v"(r) : "v"(x)); return r;
#endif
}
__device__ __forceinline__ float frcp(float x){
#if __has_builtin(__builtin_amdgcn_rcpf)
  return __builtin_amdgcn_rcpf(x);
#else
  float r; asm("v_rcp_f32 %0, %1" : "=v"(r) : "v"(x)); return r;
#endif
}

// ---------------------------------------------------------------------------
// Pack rk (256x1024) per dir into fp8 MFMA B-fragment lane order:
// byte j of lane l for tile (nt,ks) = W[k = ks*32+(l>>4)*8+j][col = nt*16+(l&15)].
// Pack k (128x1024) per dir into bf16 B-fragment order (for xzgemm), unchanged.
// ---------------------------------------------------------------------------
__global__ void prepack(const float* __restrict__ kf, const float* __restrict__ rkf,
                        const float* __restrict__ kb, const float* __restrict__ rkb,
                        unsigned char* __restrict__ rkp8, unsigned short* __restrict__ kp){
  int idx = blockIdx.x*256 + threadIdx.x;
  if (idx < RKP8_BYTES){
    int j = idx & 7, lane = (idx>>3)&63, ks = (idx>>9)&7, nt = (idx>>12)&63, d = idx>>18;
    const float* RK = d ? rkb : rkf;
    int k   = ks*32 + (lane>>4)*8 + j;
    int col = nt*16 + (lane&15);
    rkp8[idx] = f2fp8(RK[k*1024 + col]);
  } else {
    int i2 = idx - RKP8_BYTES;
    int j = i2 & 7, lane = (i2>>3)&63, ks = (i2>>9)&3, nt = (i2>>11)&63, d = i2>>17;
    const float* K = d ? kb : kf;
    int k   = ks*32 + (lane>>4)*8 + j;
    int col = nt*16 + (lane&15);
    kp[i2] = f2bf(K[k*1024 + col]);
  }
}

// ---------------------------------------------------------------------------
// xz[dir][bat][pos][1024] (fp16) = emb @ k + bias.
// Inner layout: [pos][unit j 256][gate 4] -- the recurrent kernel's lane
// (owning hidden unit j) reads its element's 4 gate pre-activations as ONE
// 8B half4 load. Grid: 128 bat x 2 dir x 5 pos-tiles of 32.
// ---------------------------------------------------------------------------
__launch_bounds__(512)
__global__ void xzgemm(const int* __restrict__ inputs, const float* __restrict__ emb,
                       const unsigned short* __restrict__ kpack,
                       const float* __restrict__ b_f, const float* __restrict__ b_b,
                       _Float16* __restrict__ xz){
  __shared__ int tokp[32];
  __shared__ __align__(16) short e_lds[32*EPITCH];
  const int bid = blockIdx.x;
  const int pt  = bid % 5;
  const int bd  = bid / 5;
  const int bat = bd & 127, dir = bd >> 7;
  const int tid = threadIdx.x, lane = tid & 63, wv = tid >> 6;
  const int lc  = lane & 15, q = lane >> 4;

  for (int i = tid; i < 32*EPITCH; i += 512) e_lds[i] = 0;
  if (tid < 32){
    int p = pt*32 + tid;
    tokp[tid] = (p < NPOS) ? inputs[bat*NPOS + p] : 0;
  }
  __syncthreads();
  for (int idx = tid; idx < 32*32; idx += 512){
    int i = idx >> 5, c4 = (idx & 31) << 2;
    int p = pt*32 + i;
    if (p < NPOS){
      float4v v = *(const float4v*)(emb + (long)tokp[i]*128 + c4);
      short4v s;
      s[0]=(short)f2bf(v[0]); s[1]=(short)f2bf(v[1]);
      s[2]=(short)f2bf(v[2]); s[3]=(short)f2bf(v[3]);
      *(short4v*)&e_lds[i*EPITCH + c4] = s;
    }
  }
  __syncthreads();

  const float* bias = dir ? b_b : b_f;
  float4v acc[2][8];
  #pragma unroll
  for (int g = 0; g < 4; ++g)
    #pragma unroll
    for (int tj = 0; tj < 2; ++tj){
      float bv = bias[g*256 + wv*32 + tj*16 + lc];
      acc[0][g*2+tj] = (float4v){bv,bv,bv,bv};
      acc[1][g*2+tj] = acc[0][g*2+tj];
    }

  const short8* KP = (const short8*)kpack + (long)dir*64*4*64;
  #pragma unroll
  for (int ks = 0; ks < 4; ++ks){
    short8 a0 = *(const short8*)&e_lds[lc*EPITCH + ks*32 + q*8];
    short8 a1 = *(const short8*)&e_lds[(16+lc)*EPITCH + ks*32 + q*8];
    #pragma unroll
    for (int n = 0; n < 8; ++n){
      int g = n >> 1, tj = n & 1;
      int nt = g*16 + wv*2 + tj;
      short8 b = KP[(nt*4 + ks)*64 + lane];
      acc[0][n] = __builtin_amdgcn_mfma_f32_16x16x32_bf16(a0, b, acc[0][n], 0, 0, 0);
      acc[1][n] = __builtin_amdgcn_mfma_f32_16x16x32_bf16(a1, b, acc[1][n], 0, 0, 0);
    }
  }

  _Float16* xzb = xz + ((long)(dir*128 + bat))*NPOS*1024;
  #pragma unroll
  for (int mt = 0; mt < 2; ++mt)
    #pragma unroll
    for (int r = 0; r < 4; ++r){
      int row = mt*16 + q*4 + r;
      int p = pt*32 + row;
      if (p < NPOS){
        #pragma unroll
        for (int tj = 0; tj < 2; ++tj){
          half4 hv;
          #pragma unroll
          for (int g = 0; g < 4; ++g) hv[g] = (_Float16)acc[mt][g*2+tj][r];
          int j = wv*32 + tj*16 + lc;   // hidden unit
          *(half4*)(xzb + (long)p*1024 + j*4) = hv;
        }
      }
    }
}

// ---------------------------------------------------------------------------
// Recurrent kernel: block = (batch, dir), 32 chains, 64 steps, K=256 (h only).
// 1024 threads (16 waves -> 4 waves/SIMD). rk ENTIRELY in VGPRs (fp8, 64
// regs/wave); h quantized to fp8 in double-buffered LDS; h/c state exact f32
// in registers; xz served from the fp16 LDS sliding window.
// Gates use shared-rcp algebra: sig(a)*tanh(b) = (1-eb)*rcp((1+ea)(1+eb)),
// cutting trans ops (16-cy issue each at wave64) from 10 to 8 per element.
// ---------------------------------------------------------------------------
__launch_bounds__(1024, 4)
__global__ void lstm_rec(const int* __restrict__ inputs, const _Float16* __restrict__ xz,
                         const unsigned char* __restrict__ rkpack8,
                         const float* __restrict__ wci_f, const float* __restrict__ wcf_f,
                         const float* __restrict__ wco_f,
                         const float* __restrict__ wci_b, const float* __restrict__ wcf_b,
                         const float* __restrict__ wco_b,
                         float* __restrict__ h_out)
{
  __shared__ int tok[NPOS];
  __shared__ __align__(16) unsigned char h8[2][NCH*HP8]; // 2 x 8.25 KB fp8
  __shared__ __align__(16) _Float16 xq[2][1024];         // query rows, slot t&1 (4 KB)
  __shared__ __align__(16) _Float16 xd[32][1024];        // doc rows, slot p&31 (64 KB)

  const int tid  = threadIdx.x;
  const int lane = tid & 63;
  const int wv   = tid >> 6;        // 0..15
  const int lc   = lane & 15;
  const int q    = lane >> 4;
  const int ju   = wv*16 + lc;      // this thread's hidden unit (0..255)
  const int bat  = blockIdx.x & 127;
  const int dir  = blockIdx.x >> 7;

  for (int p = tid; p < NPOS; p += 1024) tok[p] = inputs[bat*NPOS + p];
  for (int i = tid; i < NCH*HP8; i += 1024) h8[0][i] = 0;

  // ---- this wave's rk slice: 4 nt-tiles x 8 ks x 8B = 64 VGPRs ----
  const long* RK8 = (const long*)(rkpack8 + (long)dir*64*8*64*8);
  long rkr[8][4];                   // [ks][g], nt = g*16 + wv
  #pragma unroll
  for (int g = 0; g < 4; ++g){
    int nt = g*16 + wv;
    #pragma unroll
    for (int ks = 0; ks < 8; ++ks)
      rkr[ks][g] = RK8[(nt*8 + ks)*64 + lane];
  }

  const _Float16* xzg = xz + ((long)(dir*128 + bat))*NPOS*1024;
  const int t0 = dir ? 63 : 0;

  // prefill window: query row t0 + doc rows t0+64 .. t0+94 (32 rows, 64 KB)
  for (int i = tid; i < 32*128; i += 1024){
    int rr = i >> 7, c = i & 127;
    int p; _Float16* dst;
    if (rr == 0){ p = t0;           dst = &xq[t0 & 1][0]; }
    else        { p = t0 + 63 + rr; dst = &xd[p & 31][0]; }
    *(half8*)(dst + c*8) = *(const half8*)(xzg + (long)p*1024 + c*8);
  }

  const float* wci = dir ? wci_b : wci_f;
  const float* wcf = dir ? wcf_b : wcf_f;
  const float* wco = dir ? wco_b : wco_f;
  const float wcir = wci[ju], wcfr = wcf[ju], wcor = wco[ju];

  float hreg[2][4], creg[2][4];
  #pragma unroll
  for (int mt = 0; mt < 2; ++mt)
    #pragma unroll
    for (int r = 0; r < 4; ++r){ hreg[mt][r] = 0.f; creg[mt][r] = 0.f; }

  __syncthreads();

  for (int s = 0; s < 64; ++s){
    const int t  = dir ? (63 - s) : s;
    const int rb = s & 1, wb = rb ^ 1;
    const int tn = dir ? (t - 1) : (t + 1);

    // prefetch next-step xz rows: 2 rows x 2 KB = 4 KB; all 1024 threads load
    // one dword NOW, LDS-write just before the barrier (latency hidden under
    // this step's MFMAs+gates). Target slots are guaranteed unread this step.
    unsigned int pref = 0;
    const int prsel = tid >> 9;                    // 0 = query row, 1 = doc row
    const int prq   = tn;
    const int prd   = dir ? (tn + 64) : (tn + 94);
    if (s < 63){
      int c = tid & 511;
      int p = prsel ? prd : prq;
      pref = ((const unsigned int*)(xzg + (long)p*1024))[c];
    }

    // two mt-phases keep only 16 acc regs live at once
    #pragma unroll
    for (int mt = 0; mt < 2; ++mt){
      // acc init from LDS xz window: per r one 8B half4 = 4 gate values
      float4v acc[4];                              // [g], vector index = r
      #pragma unroll
      for (int r = 0; r < 4; ++r){
        int m = mt*16 + q*4 + r;
        const _Float16* srow = (m == 0) ? &xq[t & 1][0] : &xd[(63 + m + t) & 31][0];
        half4 hv = *(const half4*)(srow + ju*4);
        acc[0][r] = (float)hv[0];
        acc[1][r] = (float)hv[1];
        acc[2][r] = (float)hv[2];
        acc[3][r] = (float)hv[3];
      }

      // MFMA over K=256 (8 ks slices); rk fragments straight from VGPRs
      const int arow = (mt*16 + lc)*HP8;
      #pragma unroll
      for (int ks = 0; ks < 8; ++ks){
        long a = *(const long*)&h8[rb][arow + ks*32 + q*8];
        #pragma unroll
        for (int g = 0; g < 4; ++g)
          acc[g] = __builtin_amdgcn_mfma_f32_16x16x32_fp8_fp8(a, rkr[ks][g], acc[g], 0, 0, 0);
      }

      // gates (shared-rcp): C/D layout row(chain) = q*4+r, col = unit ju.
      // sig(a)*tanh(b) = (1-eb)*rcp((1+ea)(1+eb)) -- one rcp per product;
      // saturation limits exact through inf arithmetic (rcp(inf)=0).
      #pragma unroll
      for (int r = 0; r < 4; ++r){
        int m = mt*16 + q*4 + r;
        int p = (m == 0) ? t : 63 + m + t;
        bool msk = (tok[p] != 0);
        float zi = acc[0][r];
        float zf = acc[1][r];
        float zc = acc[2][r];
        float zo = acc[3][r];
        float c0 = creg[mt][r];
        float ea = fexp2(__builtin_fmaf(c0, wcir, zi) * -1.44269504f);
        float eb = fexp2(__builtin_fmaf(c0, wcfr, zf) * -1.44269504f);
        float ec = fexp2(zc * -2.88539008f);
        float it = (1.0f - ec) * frcp((1.0f + ea)*(1.0f + ec));  // i*tanh(zc)
        float fg = frcp(1.0f + eb);
        float cn = __builtin_fmaf(fg, c0, it);
        float ed = fexp2(__builtin_fmaf(cn, wcor, zo) * -1.44269504f);
        float en = fexp2(cn * -2.88539008f);
        float hn = (1.0f - en) * frcp((1.0f + ed)*(1.0f + en));  // o*tanh(cn)
        float hv = msk ? hn : hreg[mt][r];
        float cv = msk ? cn : c0;
        hreg[mt][r] = hv;
        creg[mt][r] = cv;
        h8[wb][m*HP8 + ju] = f2fp8(hv);
      }
    }

    // land the prefetched xz rows (slots free this step; read next step)
    if (s < 63){
      int c = tid & 511;
      _Float16* dst = prsel ? &xd[prd & 31][0] : &xq[prq & 1][0];
      ((unsigned int*)dst)[c] = pref;
    }

    __syncthreads();   // one barrier per step (double-buffered h + xz window)
  }

  #pragma unroll
  for (int mt = 0; mt < 2; ++mt)
    #pragma unroll
    for (int r = 0; r < 4; ++r){
      int m = mt*16 + q*4 + r;
      h_out[(((long)dir*128 + bat)*32 + m)*256 + ju] = hreg[mt][r];
    }
}

// ---------------------------------------------------------------------------
// h_avg = 0.5(h_f + h_b); cos = |q.d|/(|q||d|); softmax over 31 docs.
// ---------------------------------------------------------------------------
__global__ void finalize(const float* __restrict__ h_out, float* __restrict__ out){
  __shared__ float hav[32*256];
  __shared__ float dotl[32], sql[32];
  const int bat = blockIdx.x;
  const int tid = threadIdx.x;
  const float* hf = h_out + (long)bat*8192;
  const float* hb = h_out + (long)(128 + bat)*8192;
  for (int i = tid; i < 8192; i += 256) hav[i] = 0.5f*(hf[i] + hb[i]);
  __syncthreads();
  const int lane = tid & 63, wv = tid >> 6;
  for (int n = wv; n < 32; n += 4){
    float s1 = 0.f, s2 = 0.f;
    for (int j = lane; j < 256; j += 64){
      float a  = hav[n*256 + j];
      float qv = hav[j];
      s1 += a*qv; s2 += a*a;
    }
    #pragma unroll
    for (int off = 32; off; off >>= 1){
      s1 += __shfl_down(s1, off);
      s2 += __shfl_down(s2, off);
    }
    if (lane == 0){ dotl[n] = s1; sql[n] = s2; }
  }
  __syncthreads();
  if (wv == 0){
    float cosv = -1e30f;
    if (lane < 31)
      cosv = fabsf(dotl[lane+1]) / (sqrtf(sql[0]) * sqrtf(sql[lane+1]));
    float mx = cosv;
    #pragma unroll
    for (int off = 32; off; off >>= 1) mx = fmaxf(mx, __shfl_xor(mx, off));
    float e = (lane < 31) ? __expf(cosv - mx) : 0.f;
    float sum = e;
    #pragma unroll
    for (int off = 32; off; off >>= 1) sum += __shfl_xor(sum, off);
    if (lane < 31) out[bat*31 + lane] = e / sum;
  }
}

extern "C" void kernel_launch(void* const* d_in, const int* in_sizes, int n_in,
                              void* d_out, int out_size, void* d_ws, size_t ws_size,
                              hipStream_t stream) {
  const int*   inputs = (const int*)  d_in[0];
  const float* emb    = (const float*)d_in[1];
  const float* k_f    = (const float*)d_in[2];
  const float* rk_f   = (const float*)d_in[3];
  const float* b_f    = (const float*)d_in[4];
  const float* wci_f  = (const float*)d_in[5];
  const float* wcf_f  = (const float*)d_in[6];
  const float* wco_f  = (const float*)d_in[7];
  const float* k_b    = (const float*)d_in[8];
  const float* rk_b   = (const float*)d_in[9];
  const float* b_b    = (const float*)d_in[10];
  const float* wci_b  = (const float*)d_in[11];
  const float* wcf_b  = (const float*)d_in[12];
  const float* wco_b  = (const float*)d_in[13];

  unsigned char*  rkp8 = (unsigned char*) d_ws;
  unsigned short* kp   = (unsigned short*)((char*)d_ws + OFF_KP);
  _Float16*       xzp  = (_Float16*)     ((char*)d_ws + OFF_XZ);
  float*          hout = (float*)        ((char*)d_ws + OFF_HOUT);

  prepack<<<(RKP8_BYTES + KP_SHORTS)/256, 256, 0, stream>>>(k_f, rk_f, k_b, rk_b, rkp8, kp);
  xzgemm <<<128*2*5, 512, 0, stream>>>(inputs, emb, kp, b_f, b_b, xzp);
  lstm_rec<<<256, 1024, 0, stream>>>(inputs, xzp, rkp8,
                                     wci_f, wcf_f, wco_f,
                                     wci_b, wcf_b, wco_b, hout);
  finalize<<<128, 256, 0, stream>>>(hout, (float*)d_out);
}